// Round 2
// baseline (85.285 us; speedup 1.0000x reference)
//
#include <hip/hip_runtime.h>

// x (N,S,C,V) = (8,2048,4,64) fp32; embedding (C,K,V) = (4,512,64) fp32.
#define NROW 16384   // N*S
#define CCH  4
#define KCB  512
#define VDIM 64

typedef __attribute__((ext_vector_type(8))) short  short8;   // 8 x bf16
typedef __attribute__((ext_vector_type(4))) float  floatx4;  // MFMA acc

// round-to-nearest-even fp32 -> bf16 bits; rem = v - bf16(v)
__device__ inline unsigned short bf16h(float v, float* rem) {
    unsigned u = __float_as_uint(v);
    unsigned r = u + 0x7FFFu + ((u >> 16) & 1u);
    unsigned short h = (unsigned short)(r >> 16);
    *rem = v - __uint_as_float((unsigned)h << 16);
    return h;
}
__device__ inline unsigned short bf16r(float v) {   // RNE round only
    unsigned u = __float_as_uint(v);
    return (unsigned short)((u + 0x7FFFu + ((u >> 16) & 1u)) >> 16);
}

// Block = 512 thr (8 waves); grid = (NROW/128, CCH) = 512 blocks = 2/CU.
// LDS = eh (64 KB) + e2 (2 KB) + pkm (1 KB merge buf) = 67.5 KB -> 2 blocks/CU.
//
// SPLIT-K: waves 0-3 scan codes [0,256) over rows [0,128) (32 rows/wave,
// 2 row-groups); waves 4-7 scan codes [256,512) over the same rows. Each
// wave walks 16 tiles instead of 32 -> K-loop ds_read_b128 traffic per CU
// halves while MFMA total is unchanged. Halves merge through a 1 KB LDS
// buffer of packed (d,code) floats + one extra barrier.
//
// Packed argmin: pk = min(pk, asfloat((asuint(d) & ~511) | code)). Clearing
// 9 mantissa bits perturbs d by <~2e-3 (|d|<~40) -- inside the accepted
// bf16-noise flip band (<2e-2). Positive-d ties resolve to the lower code
// (= argmin first-occurrence); negative-d ties to the higher code, a
// within-noise event. Exact fp32 epilogue from original x/emb as before.
// LDS layout eh[(koct*512 + (code ^ koct))*8 + j]: XOR swizzle keeps both
// staging writes and fragment reads bank-conflict-free.
__global__ __launch_bounds__(512, 4)
void vq_fused(const float* __restrict__ x, const float* __restrict__ emb,
              float* __restrict__ out) {
    extern __shared__ unsigned short smem[];
    unsigned short* eh = smem;              // 32768 ushorts = 64 KB
    float* e2s = (float*)(smem + 32768);    // 512 floats = 2 KB
    float* pkm = e2s + KCB;                 // 128 rows x 2 halves = 1 KB

    const int tid  = threadIdx.x;
    const int lane = tid & 63;
    const int m    = lane & 15;
    const int quad = lane >> 4;
    const int wave = tid >> 6;
    const int c    = blockIdx.y;
    const int blockRow = blockIdx.x * 128;

    const float* embc = emb + (size_t)c * (KCB * VDIM);

    // --- stage codebook: wave covers 64 codes; 16 coalesced 1KB wave-reads ---
    {
        const int cb = wave * 64;
        const int koct = m >> 1, half = m & 1;
#pragma unroll
        for (int j = 0; j < 16; ++j) {
            const int g = cb * 16 + j * 64 + lane;       // float4 index
            const float4 t = ((const float4*)embc)[g];
            const int code = cb + j * 4 + quad;          // this lane's code
            ushort4 h4;
            h4.x = bf16r(t.x); h4.y = bf16r(t.y);
            h4.z = bf16r(t.z); h4.w = bf16r(t.w);
            const int off = (koct * 512 + (code ^ koct)) * 8 + half * 4;
            *(ushort4*)&eh[off] = h4;
            // fused exact-fp32 e2: reduce over the 16 lanes of this code
            float s = 0.f;
            s = fmaf(t.x, t.x, s); s = fmaf(t.y, t.y, s);
            s = fmaf(t.z, t.z, s); s = fmaf(t.w, t.w, s);
            s += __shfl_xor(s, 1, 64);
            s += __shfl_xor(s, 2, 64);
            s += __shfl_xor(s, 4, 64);
            s += __shfl_xor(s, 8, 64);
            if (m == 0) e2s[code] = s;
        }
    }

    // --- A fragments: 2 row-groups (32 rows) per wave, 2 k-halves, x hi/lo ---
    const int kh  = wave >> 2;                 // split-K half (code half)
    const int rb2 = blockRow + (wave & 3) * 32;
    short8 ah[2][2], al[2][2];                 // [row-group][k-half]
#pragma unroll
    for (int rg = 0; rg < 2; ++rg) {
        const int row = rb2 + rg * 16 + m;
        const float4* xr = (const float4*)(x + ((size_t)row * CCH + c) * VDIM);
#pragma unroll
        for (int h = 0; h < 2; ++h) {          // k = h*32 + quad*8 + j
            const float4 f0 = xr[h * 8 + quad * 2];
            const float4 f1 = xr[h * 8 + quad * 2 + 1];
            const float fv[8] = {f0.x, f0.y, f0.z, f0.w, f1.x, f1.y, f1.z, f1.w};
            short8 hh, ll;
#pragma unroll
            for (int j = 0; j < 8; ++j) {
                float r, d;
                hh[j] = (short)bf16h(fv[j], &r);
                ll[j] = (short)bf16h(r, &d);
            }
            ah[rg][h] = hh; al[rg][h] = ll;
        }
    }

    __syncthreads();   // barrier 1: eh/e2s ready

    float pk0[4], pk1[4];                      // packed (d,code) per row-group
#pragma unroll
    for (int j = 0; j < 4; ++j) {
        pk0[j] = __uint_as_float(0x7F7FFFFFu);
        pk1[j] = __uint_as_float(0x7F7FFFFFu);
    }

    const int mq0 = m ^ quad;                  // swizzled read indices
    const int mq1 = m ^ (quad + 4);
    const int codeLane = kh * 256 + m;

#pragma unroll 2
    for (int t = 0; t < 16; ++t) {             // 16 tiles (this wave's half)
        const int tt = kh * 16 + t;
        const short8 bh0 = *(const short8*)&eh[( quad      * 512 + tt * 16 + mq0) * 8];
        const short8 bh1 = *(const short8*)&eh[((quad + 4) * 512 + tt * 16 + mq1) * 8];
        const float e2v = e2s[tt * 16 + m];
        const int  code = codeLane + t * 16;   // == tt*16 + m

        // two independent depth-4 chains: acc = (xh + xl) . e per row-group
        floatx4 a0 = {0.f,0.f,0.f,0.f}, a1 = {0.f,0.f,0.f,0.f};
        a0 = __builtin_amdgcn_mfma_f32_16x16x32_bf16(ah[0][0], bh0, a0, 0, 0, 0);
        a1 = __builtin_amdgcn_mfma_f32_16x16x32_bf16(ah[1][0], bh0, a1, 0, 0, 0);
        a0 = __builtin_amdgcn_mfma_f32_16x16x32_bf16(al[0][0], bh0, a0, 0, 0, 0);
        a1 = __builtin_amdgcn_mfma_f32_16x16x32_bf16(al[1][0], bh0, a1, 0, 0, 0);
        a0 = __builtin_amdgcn_mfma_f32_16x16x32_bf16(ah[0][1], bh1, a0, 0, 0, 0);
        a1 = __builtin_amdgcn_mfma_f32_16x16x32_bf16(ah[1][1], bh1, a1, 0, 0, 0);
        a0 = __builtin_amdgcn_mfma_f32_16x16x32_bf16(al[0][1], bh1, a0, 0, 0, 0);
        a1 = __builtin_amdgcn_mfma_f32_16x16x32_bf16(al[1][1], bh1, a1, 0, 0, 0);

#pragma unroll
        for (int j = 0; j < 4; ++j) {
            const float d0 = fmaf(-2.0f, a0[j], e2v);
            pk0[j] = fminf(pk0[j],
                __uint_as_float((__float_as_uint(d0) & 0xFFFFFE00u) | code));
            const float d1 = fmaf(-2.0f, a1[j], e2v);
            pk1[j] = fminf(pk1[j],
                __uint_as_float((__float_as_uint(d1) & 0xFFFFFE00u) | code));
        }
    }

    // within-quad (16-lane) argmin on packed values
#pragma unroll
    for (int j = 0; j < 4; ++j) {
#pragma unroll
        for (int mask = 1; mask < 16; mask <<= 1) {
            pk0[j] = fminf(pk0[j], __shfl_xor(pk0[j], mask, 64));
            pk1[j] = fminf(pk1[j], __shfl_xor(pk1[j], mask, 64));
        }
    }

    // publish per-row winners of this code-half
    {
        const int rloc = (wave & 3) * 32;
#pragma unroll
        for (int j = 0; j < 4; ++j) {
            if (m == j) {
                pkm[(rloc + quad * 4 + j) * 2 + kh]      = pk0[j];
                pkm[(rloc + 16 + quad * 4 + j) * 2 + kh] = pk1[j];
            }
        }
    }

    __syncthreads();   // barrier 2: pkm ready

    // Epilogue: wave handles 16 rows; exact fp32 from original x and emb
    const size_t base1 = (size_t)NROW * CCH * VDIM;
    const size_t base2 = base1 + (size_t)NROW * CCH;
#pragma unroll
    for (int j = 0; j < 4; ++j) {
        const int rl   = wave * 16 + quad * 4 + j;
        const float pmin = fminf(pkm[rl * 2], pkm[rl * 2 + 1]);
        const int  code  = (int)(__float_as_uint(pmin) & 511u);  // uniform in quad
        const int  row   = blockRow + rl;
        const float4 t4 = ((const float4*)(x + ((size_t)row * CCH + c) * VDIM))[m];
        const float4 e4 = ((const float4*)(embc + (size_t)code * VDIM))[m];
        float4 w;
        w.x = (e4.x - t4.x) + t4.x;              // out0 = (output - x) + x
        w.y = (e4.y - t4.y) + t4.y;
        w.z = (e4.z - t4.z) + t4.z;
        w.w = (e4.w - t4.w) + t4.w;
        ((float4*)(out + ((size_t)row * CCH + c) * VDIM))[m] = w;
        float s = 0.f, dx;
        dx = t4.x - e4.x; s = fmaf(dx, dx, s);
        dx = t4.y - e4.y; s = fmaf(dx, dx, s);
        dx = t4.z - e4.z; s = fmaf(dx, dx, s);
        dx = t4.w - e4.w; s = fmaf(dx, dx, s);
        s += __shfl_xor(s, 1, 64);
        s += __shfl_xor(s, 2, 64);
        s += __shfl_xor(s, 4, 64);
        s += __shfl_xor(s, 8, 64);
        if (m == 0) {
            const size_t idx = (size_t)row * CCH + c;
            out[base1 + idx] = s;                // out1
            out[base2 + idx] = s;                // out2 (identical in ref)
        }
    }
}

extern "C" void kernel_launch(void* const* d_in, const int* in_sizes, int n_in,
                              void* d_out, int out_size, void* d_ws, size_t ws_size,
                              hipStream_t stream) {
    const float* x   = (const float*)d_in[0];
    const float* emb = (const float*)d_in[1];
    float* out = (float*)d_out;
    const size_t lds_bytes = 65536u + 2048u + 1024u;   // 68608 B -> 2 blocks/CU
    vq_fused<<<dim3(NROW / 128, CCH), dim3(512), lds_bytes, stream>>>(x, emb, out);
}